// Round 1
// baseline (231.491 us; speedup 1.0000x reference)
//
#include <hip/hip_runtime.h>

// Problem constants (from reference setup_inputs)
#define BB  16
#define LL  100
#define LOC 2000
#define EE  16

// SU=500, SL=0, TU=3600, TL=0
__global__ __launch_bounds__(256) void embed_kernel(
    const int*   __restrict__ traj_loc,   // (B,L)
    const float* __restrict__ mat2,       // (LOC,LOC)
    const float* __restrict__ vec,        // (B,L)
    const int*   __restrict__ traj_len,   // (B,)
    const float* __restrict__ emb_sl,     // (2,E)
    const float* __restrict__ emb_su,     // (2,E)
    const float* __restrict__ emb_tl,     // (2,E)
    const float* __restrict__ emb_tu,     // (2,E)
    float*       __restrict__ out)        // (B,L,LOC,E)
{
    const int bl = blockIdx.x;            // 0 .. B*L-1
    const int b  = bl / LL;
    const int l  = bl - b * LL;

    const bool valid = l < traj_len[b];
    const int  m     = valid ? 1 : 0;

    int row = traj_loc[bl] - 1;
    row = min(max(row, 0), LOC - 1);

    const float dt = vec[bl];
    const float wt = dt * (1.0f / 3600.0f);   // dt/(TU-TL)

    const int tid = threadIdx.x;
    const int e0  = (tid & 3) * 4;            // this thread's 4 consecutive e's
    const int j0  = tid >> 2;                 // 0..63  (j lane)

    // Per-(b,l) constants: out[j,e] = base[e] + coef[e] * ds[j]
    float base[4], coef[4];
    #pragma unroll
    for (int k = 0; k < 4; ++k) {
        const int e  = e0 + k;
        const float sl = emb_sl[m * EE + e];
        const float su = emb_su[m * EE + e];
        const float tl = emb_tl[m * EE + e];
        const float tu = emb_tu[m * EE + e];
        base[k] = sl + tl * (1.0f - wt) + tu * wt;
        coef[k] = (su - sl) * (1.0f / 500.0f); // /(SU-SL)
    }

    const float* __restrict__ rowp = mat2 + (size_t)row * LOC;
    float*       __restrict__ outp = out  + (size_t)bl * LOC * EE;

    // 64 distinct j's per iteration, 4 threads (e-groups) share each ds[j].
    for (int j = j0; j < LOC; j += 64) {
        const float ds = valid ? rowp[j] : 0.0f;
        float4 v;
        v.x = base[0] + coef[0] * ds;
        v.y = base[1] + coef[1] * ds;
        v.z = base[2] + coef[2] * ds;
        v.w = base[3] + coef[3] * ds;
        *reinterpret_cast<float4*>(outp + (size_t)j * EE + e0) = v;
    }
}

extern "C" void kernel_launch(void* const* d_in, const int* in_sizes, int n_in,
                              void* d_out, int out_size, void* d_ws, size_t ws_size,
                              hipStream_t stream) {
    const int*   traj_loc = (const int*)  d_in[0];
    const float* mat2     = (const float*)d_in[1];
    const float* vec      = (const float*)d_in[2];
    const int*   traj_len = (const int*)  d_in[3];
    const float* emb_sl   = (const float*)d_in[4];
    const float* emb_su   = (const float*)d_in[5];
    const float* emb_tl   = (const float*)d_in[6];
    const float* emb_tu   = (const float*)d_in[7];
    float* out = (float*)d_out;

    embed_kernel<<<BB * LL, 256, 0, stream>>>(
        traj_loc, mat2, vec, traj_len, emb_sl, emb_su, emb_tl, emb_tu, out);
}